// Round 7
// baseline (241.653 us; speedup 1.0000x reference)
//
#include <hip/hip_runtime.h>
#include <hip/hip_bf16.h>

// FourierLayer2dLite on gfx950.  B=16, M=N=256, I=O=64, NM=16.
// Modes: kx in {0..15,240..255} (a: kx = a<16 ? a : 224+a), ky in [0,16).
// Pipeline:
//   k_prep1: 1 block -> Eg[kc][n] bf16 (cos/-sin), CSg[v][kc] bf16 (cos/+sin),
//            Wtb[o_out][o_in] bf16
//   k1m  : Tb[b][ky][m][i] bf16x2 = (1/256) E[32x256] @ x[b,m,:,:]   (MFMA)
//   k2   : Xp[mc][b][ky][a][i] f32x2 partial DFT over m-chunk         (fp32)
//   k3   : OF[b][ky][a][o] f32x2 = sum_i (sum_mc Xp) * w  (fw read direct)
//   k4   : Gb[b][u][o][ky] bf16(re,-im) = c_ky*SC2*sum_a OF e^{+i..} (2ky/блок)
//   k5m  : Y = CS[256x32] @ Gb';  OUT = relu(Y@W + b + Y)             (MFMA)
// MFMA 16x16x32 bf16: A[m][k]: m=lane&15,k=(lane>>4)*8+j; B[k][n]: n=lane&15;
// C/D: col=lane&15, row=(lane>>4)*4+reg.

#define PI2F 6.283185307179586f

typedef __attribute__((ext_vector_type(8))) short short8v;
typedef __attribute__((ext_vector_type(4))) float f32x4;

static __device__ __forceinline__ unsigned short f_to_bf16(float f) {
  unsigned int u = __float_as_uint(f);
  u += 0x7fffu + ((u >> 16) & 1u);   // RNE (finite values)
  return (unsigned short)(u >> 16);
}
static __device__ __forceinline__ unsigned int pack_bf16(float lo, float hi) {
  return (unsigned int)f_to_bf16(lo) | ((unsigned int)f_to_bf16(hi) << 16);
}

// ---------------- k_prep1: trig + Wt tables (1 block) ----------------
__global__ __launch_bounds__(256) void k_prep1(unsigned short* __restrict__ Eg,
                                               unsigned short* __restrict__ CSg,
                                               const float* __restrict__ Wg,
                                               unsigned short* __restrict__ Wtb) {
  int t = threadIdx.x;                // n or v
#pragma unroll
  for (int ky = 0; ky < 16; ++ky) {
    int idx = (ky * t) & 255;
    float ss, cc;
    sincosf(PI2F * (float)idx * (1.0f / 256.0f), &ss, &cc);
    Eg[(2 * ky) * 256 + t]     = f_to_bf16(cc);
    Eg[(2 * ky + 1) * 256 + t] = f_to_bf16(-ss);
    CSg[t * 32 + 2 * ky]       = f_to_bf16(cc);
    CSg[t * 32 + 2 * ky + 1]   = f_to_bf16(ss);
  }
#pragma unroll
  for (int k = 0; k < 16; ++k) {
    int p = k * 256 + t;              // p = i*64 + o
    Wtb[(p & 63) * 64 + (p >> 6)] = f_to_bf16(Wg[p]);
  }
}

// ---------------- K1 (MFMA): Tb[b,ky,m,i] = (1/256) E @ x, bf16 packed ----------------
// grid 4096 = (b,m), 256 thr = 4 waves; wave w owns i-cols 16w..16w+15.
// x staged via double-buffered LDS chunks (32n x 64i fp32, float4 coalesced).
__global__ __launch_bounds__(256) void k1_mfma(const float* __restrict__ x,
                                               const unsigned short* __restrict__ Eg,
                                               unsigned int* __restrict__ Tb) {
  __shared__ __align__(16) unsigned short El[32 * 264];   // [kc][n], stride 264
  __shared__ __align__(16) float xs[2][2048];             // [n_loc][i] chunks
  int bm = blockIdx.x;
  int b = bm >> 8, m = bm & 255;
  int tid = threadIdx.x;

  {
    const unsigned int* src = reinterpret_cast<const unsigned int*>(Eg);
    unsigned int* dst = reinterpret_cast<unsigned int*>(El);
#pragma unroll
    for (int t = 0; t < 16; ++t) {
      int idx = t * 256 + tid;              // dw index in [32][128]
      dst[(idx >> 7) * 132 + (idx & 127)] = src[idx];
    }
  }

  const float* xrow = x + (size_t)bm * 16384;
  int lane = tid & 63, w = tid >> 6;
  int r16 = lane & 15, g4 = lane >> 4;

  {  // stage chunk 0
    const float4* s = reinterpret_cast<const float4*>(xrow);
    float4 v0 = s[tid], v1 = s[256 + tid];
    float4* d = reinterpret_cast<float4*>(xs[0]);
    d[tid] = v0;
    d[256 + tid] = v1;
  }
  __syncthreads();

  f32x4 z = {0.f, 0.f, 0.f, 0.f};
  f32x4 acc0 = z, acc1 = z;

#pragma unroll
  for (int c = 0; c < 8; ++c) {
    int cur = c & 1;
    if (c < 7) {                       // prefetch next chunk into other buffer
      const float4* s = reinterpret_cast<const float4*>(xrow + (c + 1) * 2048);
      float4 v0 = s[tid], v1 = s[256 + tid];
      float4* d = reinterpret_cast<float4*>(xs[cur ^ 1]);
      d[tid] = v0;
      d[256 + tid] = v1;
    }
    const float* xb = &xs[cur][g4 * 8 * 64 + (w * 16 + r16)];
    float xv[8];
#pragma unroll
    for (int j = 0; j < 8; ++j) xv[j] = xb[j * 64];
    short8v bfr;
#pragma unroll
    for (int j = 0; j < 8; ++j) bfr[j] = (short)f_to_bf16(xv[j]);
    int nb = c * 32 + g4 * 8;
    short8v a0 = *reinterpret_cast<const short8v*>(&El[r16 * 264 + nb]);
    short8v a1 = *reinterpret_cast<const short8v*>(&El[(16 + r16) * 264 + nb]);
    acc0 = __builtin_amdgcn_mfma_f32_16x16x32_bf16(a0, bfr, acc0, 0, 0, 0);
    acc1 = __builtin_amdgcn_mfma_f32_16x16x32_bf16(a1, bfr, acc1, 0, 0, 0);
    __syncthreads();
  }

  const float SC = 1.0f / 256.0f;
  int i = w * 16 + r16;
#pragma unroll
  for (int mt = 0; mt < 2; ++mt) {
    f32x4 av = (mt == 0) ? acc0 : acc1;
    int ky_a = mt * 8 + g4 * 2;
    Tb[((size_t)(b * 16 + ky_a) * 256 + m) * 64 + i]     = pack_bf16(av[0] * SC, av[1] * SC);
    Tb[((size_t)(b * 16 + ky_a + 1) * 256 + m) * 64 + i] = pack_bf16(av[2] * SC, av[3] * SC);
  }
}

// ---------------- K2: partial forward DFT over m-chunk (fp32) ----------------
// grid 1024 = (mc, bky); thread = (i-chunk of 4 complex, a-pair {ag, ag-16}).
__global__ __launch_bounds__(256) void k2_fwd_m(const unsigned int* __restrict__ Tb,
                                                float* __restrict__ Xp) {
  int bx = blockIdx.x;
  int bky = bx & 255, mc = bx >> 8;
  int m0 = mc * 64;
  int ih = threadIdx.x & 15;
  int ag = threadIdx.x >> 4;
  const uint4* Tp4 = reinterpret_cast<const uint4*>(Tb) + (size_t)bky * 4096 + ih;

  float cd1, sd1n, cd2, sd2n;
  { float ss, cc; sincosf(PI2F * (float)ag * (1.0f / 256.0f), &ss, &cc); cd1 = cc; sd1n = -ss; }
  { float ss, cc; sincosf(PI2F * (float)(ag - 16) * (1.0f / 256.0f), &ss, &cc); cd2 = cc; sd2n = -ss; }
  float c1, s1, c2, s2;
  { int t = (ag * m0) & 255; float ss, cc; sincosf(PI2F * (float)t * (1.0f / 256.0f), &ss, &cc); c1 = cc; s1 = -ss; }
  { int t = ((ag + 240) * m0) & 255; float ss, cc; sincosf(PI2F * (float)t * (1.0f / 256.0f), &ss, &cc); c2 = cc; s2 = -ss; }

  float xr1[4], xi1[4], xr2[4], xi2[4];
#pragma unroll
  for (int ii = 0; ii < 4; ++ii) { xr1[ii] = xi1[ii] = xr2[ii] = xi2[ii] = 0.0f; }

#pragma unroll 4
  for (int m = 0; m < 64; ++m) {
    uint4 q = Tp4[(size_t)(m0 + m) * 16];
    unsigned int dv[4] = {q.x, q.y, q.z, q.w};
    float tre[4], tim[4];
#pragma unroll
    for (int ii = 0; ii < 4; ++ii) {
      tre[ii] = __uint_as_float(dv[ii] << 16);
      tim[ii] = __uint_as_float(dv[ii] & 0xffff0000u);
    }
#pragma unroll
    for (int ii = 0; ii < 4; ++ii) {
      xr1[ii] += tre[ii] * c1 - tim[ii] * s1;
      xi1[ii] += tre[ii] * s1 + tim[ii] * c1;
      xr2[ii] += tre[ii] * c2 - tim[ii] * s2;
      xi2[ii] += tre[ii] * s2 + tim[ii] * c2;
    }
    float cn;
    cn = c1 * cd1 - s1 * sd1n; s1 = c1 * sd1n + s1 * cd1; c1 = cn;
    cn = c2 * cd2 - s2 * sd2n; s2 = c2 * sd2n + s2 * cd2; c2 = cn;
  }

  float* Xb = Xp + (size_t)mc * 1048576;
  float* Xp1 = Xb + ((size_t)bky * 32 + ag) * 128 + ih * 8;
  float* Xp2 = Xb + ((size_t)bky * 32 + ag + 16) * 128 + ih * 8;
  reinterpret_cast<float4*>(Xp1)[0] = make_float4(xr1[0], xi1[0], xr1[1], xi1[1]);
  reinterpret_cast<float4*>(Xp1)[1] = make_float4(xr1[2], xi1[2], xr1[3], xi1[3]);
  reinterpret_cast<float4*>(Xp2)[0] = make_float4(xr2[0], xi2[0], xr2[1], xi2[1]);
  reinterpret_cast<float4*>(Xp2)[1] = make_float4(xr2[2], xi2[2], xr2[3], xi2[3]);
}

// ---------------- K3: mode mix over i (fp32), sums 4 X partials ----------------
// fw read DIRECT (no wT): element (i,o,xx,ky,c) at (p*16+xx)*32 + ky*2 + c,
// p = i*64+o. 8B gathers at 1KB stride; ky0..7 share 64B lines -> L3-deduped.
__global__ __launch_bounds__(256) void k3_mix(const float* __restrict__ Xp,
                                              const float* __restrict__ fw1,
                                              const float* __restrict__ fw2,
                                              float* __restrict__ OF) {
  int blk = blockIdx.x;
  int kyy = blk >> 5, a = blk & 31;
  __shared__ float wre[64 * 65];
  __shared__ float wim[64 * 65];
  __shared__ float xsh[16 * 128];

  const float* w = (a < 16) ? fw1 : fw2;
  int xx = a & 15;
#pragma unroll
  for (int k = 0; k < 16; ++k) {
    int p = k * 256 + (int)threadIdx.x;      // p = i*64 + o
    float2 v = *reinterpret_cast<const float2*>(w + ((size_t)p * 16 + xx) * 32 + kyy * 2);
    int i = p >> 6, o = p & 63;
    wre[i * 65 + o] = v.x;
    wim[i * 65 + o] = v.y;
  }
  {
    int bb = threadIdx.x >> 4, icn = threadIdx.x & 15;
    size_t off = ((size_t)(bb * 16 + kyy) * 32 + a) * 128;
    float4 a0 = make_float4(0.f, 0.f, 0.f, 0.f), a1 = a0;
#pragma unroll
    for (int c = 0; c < 4; ++c) {
      const float4* xsrc = reinterpret_cast<const float4*>(Xp + (size_t)c * 1048576 + off);
      float4 q0 = xsrc[icn * 2], q1 = xsrc[icn * 2 + 1];
      a0.x += q0.x; a0.y += q0.y; a0.z += q0.z; a0.w += q0.w;
      a1.x += q1.x; a1.y += q1.y; a1.z += q1.z; a1.w += q1.w;
    }
    float4* xdst = reinterpret_cast<float4*>(xsh + bb * 128);
    xdst[icn * 2]     = a0;
    xdst[icn * 2 + 1] = a1;
  }
  __syncthreads();

  int o = threadIdx.x & 63, bg = threadIdx.x >> 6;
#pragma unroll
  for (int bb = 0; bb < 4; ++bb) {
    int b = bg * 4 + bb;
    float ore = 0.0f, oim = 0.0f;
    for (int i = 0; i < 64; ++i) {
      float xr = xsh[b * 128 + 2 * i], xi = xsh[b * 128 + 2 * i + 1];
      float wr = wre[i * 65 + o],     wi = wim[i * 65 + o];
      ore += xr * wr - xi * wi;
      oim += xr * wi + xi * wr;
    }
    reinterpret_cast<float2*>(OF)[(((size_t)b * 16 + kyy) * 32 + a) * 64 + o] =
        make_float2(ore, oim);
  }
}

// ---------------- K4: inverse DFT over kx; writes Gb bf16 [b][u][o][ky] ----------------
// grid 2048 = (b, ug of 16 u, ky-chunk of 2); folds c_ky, SC2, and -im.
// LDS 34KB -> 4 blocks/CU.
__global__ __launch_bounds__(256) void k4_inv_kx(const float* __restrict__ OF,
                                                 unsigned int* __restrict__ Gbd) {
  int bx = blockIdx.x;
  int b = bx >> 7, ug = (bx >> 3) & 15, kyc = bx & 7;
  __shared__ float ofs[8192];          // [2ky][32a][64o] float2 (32KB)
  __shared__ float ct[256], st[256];
  {
    float ssv, ccv;
    sincosf(PI2F * (float)threadIdx.x * (1.0f / 256.0f), &ssv, &ccv);
    ct[threadIdx.x] = ccv;
    st[threadIdx.x] = ssv;
  }
  {
    const float4* src = reinterpret_cast<const float4*>(
        OF + ((size_t)b * 16 + kyc * 2) * 4096);
    float4* dst = reinterpret_cast<float4*>(ofs);
#pragma unroll
    for (int k = 0; k < 8; ++k) dst[k * 256 + threadIdx.x] = src[k * 256 + threadIdx.x];
  }
  __syncthreads();

  int o = threadIdx.x & 63, us = threadIdx.x >> 6;
  int u0 = ug * 16 + us * 4;
  const float SC2 = 0.002772904280510622f;   // sqrt(256*129)/65536

  float accr[4][2], acci[4][2];
#pragma unroll
  for (int du = 0; du < 4; ++du)
#pragma unroll
    for (int kyl = 0; kyl < 2; ++kyl) { accr[du][kyl] = 0.0f; acci[du][kyl] = 0.0f; }

  for (int a = 0; a < 32; ++a) {
    int kx = (a < 16) ? a : (224 + a);
    float ofr[2], ofi[2];
#pragma unroll
    for (int kyl = 0; kyl < 2; ++kyl) {
      ofr[kyl] = ofs[((kyl * 32 + a) * 64 + o) * 2];
      ofi[kyl] = ofs[((kyl * 32 + a) * 64 + o) * 2 + 1];
    }
#pragma unroll
    for (int du = 0; du < 4; ++du) {
      int t = (kx * (u0 + du)) & 255;
      float cv = ct[t], sv = st[t];
#pragma unroll
      for (int kyl = 0; kyl < 2; ++kyl) {
        accr[du][kyl] += ofr[kyl] * cv - ofi[kyl] * sv;
        acci[du][kyl] += ofr[kyl] * sv + ofi[kyl] * cv;
      }
    }
  }
#pragma unroll
  for (int du = 0; du < 4; ++du) {
    int u = u0 + du;
    unsigned int wv[2];
#pragma unroll
    for (int kyl = 0; kyl < 2; ++kyl) {
      int ky = kyc * 2 + kyl;
      float sc = SC2 * ((ky == 0) ? 1.0f : 2.0f);
      wv[kyl] = pack_bf16(accr[du][kyl] * sc, -acci[du][kyl] * sc);
    }
    uint2 pk; pk.x = wv[0]; pk.y = wv[1];
    *reinterpret_cast<uint2*>(
        &Gbd[(((size_t)b * 256 + u) * 64 + o) * 16 + kyc * 2]) = pk;
  }
}

// ---------------- K5 (MFMA): Y = CS @ G'; OUT = relu(Y@W + b + Y) ----------------
// grid 4096 = (b,u), 256 thr = 4 waves; wave w owns v-rows 64w..64w+63.
// All yl traffic is wave-local -> no barriers. Coalesced float4 stores.
__global__ __launch_bounds__(256) void k5_mfma(const unsigned short* __restrict__ Gb,
                                               const unsigned short* __restrict__ CSg,
                                               const unsigned short* __restrict__ Wtb,
                                               const float* __restrict__ bias,
                                               float* __restrict__ out) {
  __shared__ __align__(16) unsigned short yl[256 * 72];   // 36864 B

  int blk = blockIdx.x;
  int tid = threadIdx.x;
  int lane = tid & 63, w = tid >> 6;
  int r16 = lane & 15, g4 = lane >> 4;
  int kc0 = g4 * 8;

  f32x4 z = {0.f, 0.f, 0.f, 0.f};
  f32x4 acc[4][4];

  // ---- phase A: A = CS rows v, B = G' rows kc cols o ----
  short8v af[4], bfx[4];
#pragma unroll
  for (int vt = 0; vt < 4; ++vt)
    af[vt] = *reinterpret_cast<const short8v*>(&CSg[(w * 64 + vt * 16 + r16) * 32 + kc0]);
#pragma unroll
  for (int ot = 0; ot < 4; ++ot)
    bfx[ot] = *reinterpret_cast<const short8v*>(
        &Gb[((size_t)blk * 64 + ot * 16 + r16) * 32 + kc0]);
#pragma unroll
  for (int vt = 0; vt < 4; ++vt)
#pragma unroll
    for (int ot = 0; ot < 4; ++ot)
      acc[vt][ot] = __builtin_amdgcn_mfma_f32_16x16x32_bf16(af[vt], bfx[ot], z, 0, 0, 0);

  // Y -> LDS bf16 (own-wave rows only)
#pragma unroll
  for (int vt = 0; vt < 4; ++vt)
#pragma unroll
    for (int ot = 0; ot < 4; ++ot)
#pragma unroll
      for (int r = 0; r < 4; ++r)
        yl[(w * 64 + vt * 16 + g4 * 4 + r) * 72 + ot * 16 + r16] = f_to_bf16(acc[vt][ot][r]);

  // ---- phase B: acc += bias, then += Y @ W ----
#pragma unroll
  for (int ot = 0; ot < 4; ++ot) {
    float bv = bias[ot * 16 + r16];
#pragma unroll
    for (int vt = 0; vt < 4; ++vt)
#pragma unroll
      for (int r = 0; r < 4; ++r) acc[vt][ot][r] += bv;
  }

#pragma unroll
  for (int ks = 0; ks < 2; ++ks) {
    int k0 = ks * 32 + kc0;
    short8v ya[4], wb[4];
#pragma unroll
    for (int vt = 0; vt < 4; ++vt)
      ya[vt] = *reinterpret_cast<const short8v*>(&yl[(w * 64 + vt * 16 + r16) * 72 + k0]);
#pragma unroll
    for (int ot = 0; ot < 4; ++ot)
      wb[ot] = *reinterpret_cast<const short8v*>(&Wtb[(ot * 16 + r16) * 64 + k0]);
#pragma unroll
    for (int vt = 0; vt < 4; ++vt)
#pragma unroll
      for (int ot = 0; ot < 4; ++ot)
        acc[vt][ot] = __builtin_amdgcn_mfma_f32_16x16x32_bf16(ya[vt], wb[ot], acc[vt][ot], 0, 0, 0);
  }

  // ---- epilogue: relu -> wave-local LDS transpose -> coalesced float4 stores ----
  float* ob = out + (size_t)blk * 16384;
  float* tw = reinterpret_cast<float*>(&yl[w * 4608]);   // own 9216B region, reuse
#pragma unroll
  for (int vt = 0; vt < 4; ++vt) {
#pragma unroll
    for (int ot = 0; ot < 4; ++ot)
#pragma unroll
      for (int r = 0; r < 4; ++r)
        tw[(g4 * 4 + r) * 68 + ot * 16 + r16] = fmaxf(acc[vt][ot][r], 0.0f);
    float* obase = ob + (size_t)(w * 64 + vt * 16) * 64;
#pragma unroll
    for (int q = 0; q < 4; ++q) {
      float4 vv = *reinterpret_cast<const float4*>(
          &tw[(q * 4 + (lane >> 4)) * 68 + (lane & 15) * 4]);
      *reinterpret_cast<float4*>(&obase[q * 256 + lane * 4]) = vv;
    }
  }
}

extern "C" void kernel_launch(void* const* d_in, const int* in_sizes, int n_in,
                              void* d_out, int out_size, void* d_ws, size_t ws_size,
                              hipStream_t stream) {
  const float* x   = (const float*)d_in[0];
  const float* fw1 = (const float*)d_in[1];
  const float* fw2 = (const float*)d_in[2];
  const float* W   = (const float*)d_in[3];
  const float* bb  = (const float*)d_in[4];
  float* out = (float*)d_out;

  float* ws = (float*)d_ws;
  unsigned int* Tb   = (unsigned int*)(ws + 4194304);        // 4,194,304 dw (16.8 MB)
  float* Xp          = ws + 8388608;                         // 4 x 1,048,576 f (16.8 MB)
  float* OF          = ws + 12582912;                        // 1,048,576 f (4.2 MB)
  unsigned int* Gb   = (unsigned int*)(ws + 13631488);       // 4,194,304 dw (16.8 MB)
  unsigned short* Eg  = (unsigned short*)(ws + 17825792);    // 8192 u16
  unsigned short* CSg = Eg + 8192;                           // 8192 u16
  unsigned short* Wtb = CSg + 8192;                          // 4096 u16

  hipLaunchKernelGGL(k_prep1,  dim3(1),    dim3(256), 0, stream, Eg, CSg, W, Wtb);
  hipLaunchKernelGGL(k1_mfma,  dim3(4096), dim3(256), 0, stream, x, Eg, Tb);
  hipLaunchKernelGGL(k2_fwd_m, dim3(1024), dim3(256), 0, stream, Tb, Xp);
  hipLaunchKernelGGL(k3_mix,   dim3(512),  dim3(256), 0, stream, Xp, fw1, fw2, OF);
  hipLaunchKernelGGL(k4_inv_kx,dim3(2048), dim3(256), 0, stream, OF, Gb);
  hipLaunchKernelGGL(k5_mfma,  dim3(4096), dim3(256), 0, stream,
                     (const unsigned short*)Gb, CSg, Wtb, bb, out);
}

// Round 8
// 234.553 us; speedup vs baseline: 1.0303x; 1.0303x over previous
//
#include <hip/hip_runtime.h>
#include <hip/hip_bf16.h>

// FourierLayer2dLite on gfx950.  B=16, M=N=256, I=O=64, NM=16.
// Modes: kx in {0..15,240..255} (a: kx = a<16 ? a : 224+a), ky in [0,16).
// Pipeline:
//   k_prep: blocks 0..255 -> wT[ky][a][i][o] f32x2; block 256 -> Eg/CSg/Wtb bf16
//           (Eg pre-scaled by 1/256)
//   k1m  : Tb[b][ky][m][i] bf16x2 = E' @ x[b,m,:,:]   (MFMA; XOR-swizzled LDS)
//   k2   : Xp[mc][b][ky][a][i] f32x2 partial DFT over m-chunk         (fp32)
//   k3   : OF[b][ky][a][o] f32x2 = sum_i (sum_mc Xp) * w (wT staged)  (fp32)
//   k4   : Gb[b][u][chunk][o] bf16(re,-im)x4ky = c_ky*SC2*sum_a OF e^{+i..}
//   k5m  : Y = CS[256x32] @ Gb';  OUT = relu(Y@W + b + Y)             (MFMA)
// MFMA 16x16x32 bf16: A[m][k]: m=lane&15,k=(lane>>4)*8+j; B[k][n]: n=lane&15;
// C/D: col=lane&15, row=(lane>>4)*4+reg.

#define PI2F 6.283185307179586f

typedef __attribute__((ext_vector_type(8))) short short8v;
typedef __attribute__((ext_vector_type(4))) float f32x4;

static __device__ __forceinline__ unsigned short f_to_bf16(float f) {
  unsigned int u = __float_as_uint(f);
  u += 0x7fffu + ((u >> 16) & 1u);   // RNE (finite values)
  return (unsigned short)(u >> 16);
}
static __device__ __forceinline__ unsigned int pack_bf16(float lo, float hi) {
  return (unsigned int)f_to_bf16(lo) | ((unsigned int)f_to_bf16(hi) << 16);
}

// ---------------- k_prep: wT (blocks 0..255) + tables (block 256) ----------------
__global__ __launch_bounds__(256) void k_prep(const float* __restrict__ fw1,
                                              const float* __restrict__ fw2,
                                              float2* __restrict__ wT,
                                              unsigned short* __restrict__ Eg,
                                              unsigned short* __restrict__ CSg,
                                              const float* __restrict__ Wg,
                                              unsigned short* __restrict__ Wtb) {
  int t = threadIdx.x;
  if (blockIdx.x == 256) {             // trig + Wt tables
    const float SC = 1.0f / 256.0f;    // fwd norm folded into E
#pragma unroll
    for (int ky = 0; ky < 16; ++ky) {
      int idx = (ky * t) & 255;
      float ss, cc;
      sincosf(PI2F * (float)idx * (1.0f / 256.0f), &ss, &cc);
      Eg[(2 * ky) * 256 + t]     = f_to_bf16(cc * SC);
      Eg[(2 * ky + 1) * 256 + t] = f_to_bf16(-ss * SC);
      CSg[t * 32 + 2 * ky]       = f_to_bf16(cc);
      CSg[t * 32 + 2 * ky + 1]   = f_to_bf16(ss);
    }
#pragma unroll
    for (int k = 0; k < 16; ++k) {
      int p = k * 256 + t;             // p = i*64 + o
      Wtb[(p & 63) * 64 + (p >> 6)] = f_to_bf16(Wg[p]);
    }
    return;
  }
  int a  = blockIdx.x >> 3;
  int ic = blockIdx.x & 7;
  const float* w = (a < 16) ? fw1 : fw2;
  int xx = a & 15;
#pragma unroll
  for (int k = 0; k < 2; ++k) {
    int p = k * 256 + t;
    int i = ic * 8 + (p >> 6);
    int o = p & 63;
    const float4* s4 = reinterpret_cast<const float4*>(
        w + ((((size_t)i * 64 + o) * 16 + xx) * 16) * 2);
#pragma unroll
    for (int j = 0; j < 8; ++j) {
      float4 q = s4[j];
      wT[(((size_t)(2 * j) * 32 + a) * 64 + i) * 64 + o]     = make_float2(q.x, q.y);
      wT[(((size_t)(2 * j + 1) * 32 + a) * 64 + i) * 64 + o] = make_float2(q.z, q.w);
    }
  }
}

// ---------------- K1 (MFMA): Tb[b,ky,m,i] = E' @ x, bf16 packed ----------------
// grid 4096 = (b,m), 256 thr = 4 waves; wave w owns i-cols 16w..16w+15.
// x staged via double-buffered XOR-swizzled LDS: element [row n][col i] stored at
// col' = i ^ ((n>>3)<<4). Writes stay contiguous (uniform key per instr); reads
// have bank = ((w^g4)&1)*16 + r16 -> 2 lanes/bank (free).
__global__ __launch_bounds__(256) void k1_mfma(const float* __restrict__ x,
                                               const unsigned short* __restrict__ Eg,
                                               unsigned int* __restrict__ Tb) {
  __shared__ __align__(16) unsigned short El[32 * 264];   // [kc][n], stride 264
  __shared__ __align__(16) float xs[2][2048];             // [n_loc][i] swizzled
  int bm = blockIdx.x;
  int b = bm >> 8, m = bm & 255;
  int tid = threadIdx.x;

  {
    const unsigned int* src = reinterpret_cast<const unsigned int*>(Eg);
    unsigned int* dst = reinterpret_cast<unsigned int*>(El);
#pragma unroll
    for (int t = 0; t < 16; ++t) {
      int idx = t * 256 + tid;              // dw index in [32][128]
      dst[(idx >> 7) * 132 + (idx & 127)] = src[idx];
    }
  }

  const float* xrow = x + (size_t)bm * 16384;
  int lane = tid & 63, w = tid >> 6;
  int r16 = lane & 15, g4 = lane >> 4;

  int r0 = tid >> 4;                   // rows 0..15 (first 4KB)
  int c4 = (tid & 15) * 4;
  int off0 = r0 * 64 + (c4 ^ (((r0 >> 3) & 3) << 4));
  int r1 = 16 + r0;                    // rows 16..31
  int off1 = r1 * 64 + (c4 ^ (((r1 >> 3) & 3) << 4));
  int colr = (w * 16 + r16) ^ (g4 << 4);   // read col (key == g4 since n>>3 == g4)

  {  // stage chunk 0
    const float4* s = reinterpret_cast<const float4*>(xrow);
    float4 v0 = s[tid], v1 = s[256 + tid];
    *reinterpret_cast<float4*>(&xs[0][off0]) = v0;
    *reinterpret_cast<float4*>(&xs[0][off1]) = v1;
  }
  __syncthreads();

  f32x4 z = {0.f, 0.f, 0.f, 0.f};
  f32x4 acc0 = z, acc1 = z;

#pragma unroll
  for (int c = 0; c < 8; ++c) {
    int cur = c & 1;
    if (c < 7) {                       // prefetch next chunk into other buffer
      const float4* s = reinterpret_cast<const float4*>(xrow + (c + 1) * 2048);
      float4 v0 = s[tid], v1 = s[256 + tid];
      *reinterpret_cast<float4*>(&xs[cur ^ 1][off0]) = v0;
      *reinterpret_cast<float4*>(&xs[cur ^ 1][off1]) = v1;
    }
    const float* xb = &xs[cur][g4 * 8 * 64 + colr];
    float xv[8];
#pragma unroll
    for (int j = 0; j < 8; ++j) xv[j] = xb[j * 64];
    short8v bfr;
#pragma unroll
    for (int j = 0; j < 8; ++j) bfr[j] = (short)f_to_bf16(xv[j]);
    int nb = c * 32 + g4 * 8;
    short8v a0 = *reinterpret_cast<const short8v*>(&El[r16 * 264 + nb]);
    short8v a1 = *reinterpret_cast<const short8v*>(&El[(16 + r16) * 264 + nb]);
    acc0 = __builtin_amdgcn_mfma_f32_16x16x32_bf16(a0, bfr, acc0, 0, 0, 0);
    acc1 = __builtin_amdgcn_mfma_f32_16x16x32_bf16(a1, bfr, acc1, 0, 0, 0);
    __syncthreads();
  }

  int i = w * 16 + r16;
#pragma unroll
  for (int mt = 0; mt < 2; ++mt) {
    f32x4 av = (mt == 0) ? acc0 : acc1;
    int ky_a = mt * 8 + g4 * 2;
    Tb[((size_t)(b * 16 + ky_a) * 256 + m) * 64 + i]     = pack_bf16(av[0], av[1]);
    Tb[((size_t)(b * 16 + ky_a + 1) * 256 + m) * 64 + i] = pack_bf16(av[2], av[3]);
  }
}

// ---------------- K2: partial forward DFT over m-chunk (fp32) ----------------
__global__ __launch_bounds__(256) void k2_fwd_m(const unsigned int* __restrict__ Tb,
                                                float* __restrict__ Xp) {
  int bx = blockIdx.x;
  int bky = bx & 255, mc = bx >> 8;
  int m0 = mc * 64;
  int ih = threadIdx.x & 15;
  int ag = threadIdx.x >> 4;
  const uint4* Tp4 = reinterpret_cast<const uint4*>(Tb) + (size_t)bky * 4096 + ih;

  float cd1, sd1n, cd2, sd2n;
  { float ss, cc; sincosf(PI2F * (float)ag * (1.0f / 256.0f), &ss, &cc); cd1 = cc; sd1n = -ss; }
  { float ss, cc; sincosf(PI2F * (float)(ag - 16) * (1.0f / 256.0f), &ss, &cc); cd2 = cc; sd2n = -ss; }
  float c1, s1, c2, s2;
  { int t = (ag * m0) & 255; float ss, cc; sincosf(PI2F * (float)t * (1.0f / 256.0f), &ss, &cc); c1 = cc; s1 = -ss; }
  { int t = ((ag + 240) * m0) & 255; float ss, cc; sincosf(PI2F * (float)t * (1.0f / 256.0f), &ss, &cc); c2 = cc; s2 = -ss; }

  float xr1[4], xi1[4], xr2[4], xi2[4];
#pragma unroll
  for (int ii = 0; ii < 4; ++ii) { xr1[ii] = xi1[ii] = xr2[ii] = xi2[ii] = 0.0f; }

#pragma unroll 4
  for (int m = 0; m < 64; ++m) {
    uint4 q = Tp4[(size_t)(m0 + m) * 16];
    unsigned int dv[4] = {q.x, q.y, q.z, q.w};
    float tre[4], tim[4];
#pragma unroll
    for (int ii = 0; ii < 4; ++ii) {
      tre[ii] = __uint_as_float(dv[ii] << 16);
      tim[ii] = __uint_as_float(dv[ii] & 0xffff0000u);
    }
#pragma unroll
    for (int ii = 0; ii < 4; ++ii) {
      xr1[ii] += tre[ii] * c1 - tim[ii] * s1;
      xi1[ii] += tre[ii] * s1 + tim[ii] * c1;
      xr2[ii] += tre[ii] * c2 - tim[ii] * s2;
      xi2[ii] += tre[ii] * s2 + tim[ii] * c2;
    }
    float cn;
    cn = c1 * cd1 - s1 * sd1n; s1 = c1 * sd1n + s1 * cd1; c1 = cn;
    cn = c2 * cd2 - s2 * sd2n; s2 = c2 * sd2n + s2 * cd2; c2 = cn;
  }

  float* Xb = Xp + (size_t)mc * 1048576;
  float* Xp1 = Xb + ((size_t)bky * 32 + ag) * 128 + ih * 8;
  float* Xp2 = Xb + ((size_t)bky * 32 + ag + 16) * 128 + ih * 8;
  reinterpret_cast<float4*>(Xp1)[0] = make_float4(xr1[0], xi1[0], xr1[1], xi1[1]);
  reinterpret_cast<float4*>(Xp1)[1] = make_float4(xr1[2], xi1[2], xr1[3], xi1[3]);
  reinterpret_cast<float4*>(Xp2)[0] = make_float4(xr2[0], xi2[0], xr2[1], xi2[1]);
  reinterpret_cast<float4*>(Xp2)[1] = make_float4(xr2[2], xi2[2], xr2[3], xi2[3]);
}

// ---------------- K3: mode mix over i (fp32), sums 4 X partials; wT staged ----------------
__global__ __launch_bounds__(256) void k3_mix(const float* __restrict__ Xp,
                                              const float* __restrict__ wT,
                                              float* __restrict__ OF) {
  int blk = blockIdx.x;
  int kyy = blk >> 5, a = blk & 31;
  __shared__ float wre[64 * 65];
  __shared__ float wim[64 * 65];
  __shared__ float xsh[16 * 128];

  const float2* wsrc = reinterpret_cast<const float2*>(wT) + (size_t)(kyy * 32 + a) * 4096;
#pragma unroll
  for (int k = 0; k < 16; ++k) {
    int p = k * 256 + (int)threadIdx.x;
    float2 v = wsrc[p];
    int i = p >> 6, o = p & 63;
    wre[i * 65 + o] = v.x;
    wim[i * 65 + o] = v.y;
  }
  {
    int bb = threadIdx.x >> 4, icn = threadIdx.x & 15;
    size_t off = ((size_t)(bb * 16 + kyy) * 32 + a) * 128;
    float4 a0 = make_float4(0.f, 0.f, 0.f, 0.f), a1 = a0;
#pragma unroll
    for (int c = 0; c < 4; ++c) {
      const float4* xsrc = reinterpret_cast<const float4*>(Xp + (size_t)c * 1048576 + off);
      float4 q0 = xsrc[icn * 2], q1 = xsrc[icn * 2 + 1];
      a0.x += q0.x; a0.y += q0.y; a0.z += q0.z; a0.w += q0.w;
      a1.x += q1.x; a1.y += q1.y; a1.z += q1.z; a1.w += q1.w;
    }
    float4* xdst = reinterpret_cast<float4*>(xsh + bb * 128);
    xdst[icn * 2]     = a0;
    xdst[icn * 2 + 1] = a1;
  }
  __syncthreads();

  int o = threadIdx.x & 63, bg = threadIdx.x >> 6;
#pragma unroll
  for (int bb = 0; bb < 4; ++bb) {
    int b = bg * 4 + bb;
    float ore = 0.0f, oim = 0.0f;
    for (int i = 0; i < 64; ++i) {
      float xr = xsh[b * 128 + 2 * i], xi = xsh[b * 128 + 2 * i + 1];
      float wr = wre[i * 65 + o],     wi = wim[i * 65 + o];
      ore += xr * wr - xi * wi;
      oim += xr * wi + xi * wr;
    }
    reinterpret_cast<float2*>(OF)[(((size_t)b * 16 + kyy) * 32 + a) * 64 + o] =
        make_float2(ore, oim);
  }
}

// ---------------- K4: inverse DFT over kx; Gb bf16 [b][u][chunk][o][4ky] ----------------
// grid 1024 = (b, ug of 16 u, ky-chunk of 4). No OF staging: direct coalesced
// 512B float2 reads (L2-hot); only ct/st in LDS (2KB) -> high occupancy.
// uint4 writes: lanes o consecutive -> 1KB contiguous per wave.
__global__ __launch_bounds__(256) void k4_inv_kx(const float* __restrict__ OF,
                                                 uint4* __restrict__ Gb4) {
  int bx = blockIdx.x;
  int b = bx >> 6, ug = (bx >> 2) & 15, chunk = bx & 3;
  __shared__ float ct[256], st[256];
  {
    float ssv, ccv;
    sincosf(PI2F * (float)threadIdx.x * (1.0f / 256.0f), &ssv, &ccv);
    ct[threadIdx.x] = ccv;
    st[threadIdx.x] = ssv;
  }
  __syncthreads();

  int o = threadIdx.x & 63, us = threadIdx.x >> 6;
  int u0 = ug * 16 + us * 4;
  const float SC2 = 0.002772904280510622f;   // sqrt(256*129)/65536
  const float2* OFb = reinterpret_cast<const float2*>(OF) +
                      ((size_t)b * 16 + chunk * 4) * 2048;   // [4ky][32a][64o]

  float accr[4][4], acci[4][4];
#pragma unroll
  for (int du = 0; du < 4; ++du)
#pragma unroll
    for (int kyl = 0; kyl < 4; ++kyl) { accr[du][kyl] = 0.0f; acci[du][kyl] = 0.0f; }

  for (int a = 0; a < 32; ++a) {
    int kx = (a < 16) ? a : (224 + a);
    float ofr[4], ofi[4];
#pragma unroll
    for (int kyl = 0; kyl < 4; ++kyl) {
      float2 v = OFb[(kyl * 32 + a) * 64 + o];
      ofr[kyl] = v.x; ofi[kyl] = v.y;
    }
#pragma unroll
    for (int du = 0; du < 4; ++du) {
      int t = (kx * (u0 + du)) & 255;
      float cv = ct[t], sv = st[t];
#pragma unroll
      for (int kyl = 0; kyl < 4; ++kyl) {
        accr[du][kyl] += ofr[kyl] * cv - ofi[kyl] * sv;
        acci[du][kyl] += ofr[kyl] * sv + ofi[kyl] * cv;
      }
    }
  }
#pragma unroll
  for (int du = 0; du < 4; ++du) {
    int u = u0 + du;
    unsigned int wv[4];
#pragma unroll
    for (int kyl = 0; kyl < 4; ++kyl) {
      int ky = chunk * 4 + kyl;
      float sc = SC2 * ((ky == 0) ? 1.0f : 2.0f);
      wv[kyl] = pack_bf16(accr[du][kyl] * sc, -acci[du][kyl] * sc);
    }
    uint4 pk; pk.x = wv[0]; pk.y = wv[1]; pk.z = wv[2]; pk.w = wv[3];
    Gb4[(((size_t)b * 256 + u) * 4 + chunk) * 64 + o] = pk;
  }
}

// ---------------- K5 (MFMA): Y = CS @ G'; OUT = relu(Y@W + b + Y) ----------------
// grid 4096 = (b,u), 256 thr = 4 waves; wave w owns v-rows 64w..64w+63.
// Gb layout [b][u][chunk][o][4ky]: lane (g4,r16) reads chunk=g4 -> coalesced.
__global__ __launch_bounds__(256) void k5_mfma(const unsigned short* __restrict__ Gb,
                                               const unsigned short* __restrict__ CSg,
                                               const unsigned short* __restrict__ Wtb,
                                               const float* __restrict__ bias,
                                               float* __restrict__ out) {
  __shared__ __align__(16) unsigned short yl[256 * 72];   // 36864 B

  int blk = blockIdx.x;
  int tid = threadIdx.x;
  int lane = tid & 63, w = tid >> 6;
  int r16 = lane & 15, g4 = lane >> 4;
  int kc0 = g4 * 8;

  f32x4 z = {0.f, 0.f, 0.f, 0.f};
  f32x4 acc[4][4];

  // ---- phase A: A = CS rows v, B = G' rows kc cols o ----
  short8v af[4], bfx[4];
#pragma unroll
  for (int vt = 0; vt < 4; ++vt)
    af[vt] = *reinterpret_cast<const short8v*>(&CSg[(w * 64 + vt * 16 + r16) * 32 + kc0]);
#pragma unroll
  for (int ot = 0; ot < 4; ++ot)
    bfx[ot] = *reinterpret_cast<const short8v*>(
        &Gb[(((size_t)blk * 4 + g4) * 64 + ot * 16 + r16) * 8]);
#pragma unroll
  for (int vt = 0; vt < 4; ++vt)
#pragma unroll
    for (int ot = 0; ot < 4; ++ot)
      acc[vt][ot] = __builtin_amdgcn_mfma_f32_16x16x32_bf16(af[vt], bfx[ot], z, 0, 0, 0);

  // Y -> LDS bf16 (own-wave rows only)
#pragma unroll
  for (int vt = 0; vt < 4; ++vt)
#pragma unroll
    for (int ot = 0; ot < 4; ++ot)
#pragma unroll
      for (int r = 0; r < 4; ++r)
        yl[(w * 64 + vt * 16 + g4 * 4 + r) * 72 + ot * 16 + r16] = f_to_bf16(acc[vt][ot][r]);

  // ---- phase B: acc += bias, then += Y @ W ----
#pragma unroll
  for (int ot = 0; ot < 4; ++ot) {
    float bv = bias[ot * 16 + r16];
#pragma unroll
    for (int vt = 0; vt < 4; ++vt)
#pragma unroll
      for (int r = 0; r < 4; ++r) acc[vt][ot][r] += bv;
  }

#pragma unroll
  for (int ks = 0; ks < 2; ++ks) {
    int k0 = ks * 32 + kc0;
    short8v ya[4], wb[4];
#pragma unroll
    for (int vt = 0; vt < 4; ++vt)
      ya[vt] = *reinterpret_cast<const short8v*>(&yl[(w * 64 + vt * 16 + r16) * 72 + k0]);
#pragma unroll
    for (int ot = 0; ot < 4; ++ot)
      wb[ot] = *reinterpret_cast<const short8v*>(&Wtb[(ot * 16 + r16) * 64 + k0]);
#pragma unroll
    for (int vt = 0; vt < 4; ++vt)
#pragma unroll
      for (int ot = 0; ot < 4; ++ot)
        acc[vt][ot] = __builtin_amdgcn_mfma_f32_16x16x32_bf16(ya[vt], wb[ot], acc[vt][ot], 0, 0, 0);
  }

  // ---- epilogue: relu -> wave-local LDS transpose -> coalesced float4 stores ----
  float* ob = out + (size_t)blk * 16384;
  float* tw = reinterpret_cast<float*>(&yl[w * 4608]);   // own 9216B region, reuse
#pragma unroll
  for (int vt = 0; vt < 4; ++vt) {
#pragma unroll
    for (int ot = 0; ot < 4; ++ot)
#pragma unroll
      for (int r = 0; r < 4; ++r)
        tw[(g4 * 4 + r) * 68 + ot * 16 + r16] = fmaxf(acc[vt][ot][r], 0.0f);
    float* obase = ob + (size_t)(w * 64 + vt * 16) * 64;
#pragma unroll
    for (int q = 0; q < 4; ++q) {
      float4 vv = *reinterpret_cast<const float4*>(
          &tw[(q * 4 + (lane >> 4)) * 68 + (lane & 15) * 4]);
      *reinterpret_cast<float4*>(&obase[q * 256 + lane * 4]) = vv;
    }
  }
}

extern "C" void kernel_launch(void* const* d_in, const int* in_sizes, int n_in,
                              void* d_out, int out_size, void* d_ws, size_t ws_size,
                              hipStream_t stream) {
  const float* x   = (const float*)d_in[0];
  const float* fw1 = (const float*)d_in[1];
  const float* fw2 = (const float*)d_in[2];
  const float* W   = (const float*)d_in[3];
  const float* bb  = (const float*)d_in[4];
  float* out = (float*)d_out;

  float* ws = (float*)d_ws;
  float* wT          = ws;                                   // 4,194,304 f (16 MB)
  unsigned int* Tb   = (unsigned int*)(ws + 4194304);        // 4,194,304 dw (16.8 MB)
  float* Xp          = ws + 8388608;                         // 4 x 1,048,576 f (16.8 MB)
  float* OF          = ws + 12582912;                        // 1,048,576 f (4.2 MB)
  unsigned int* Gb   = (unsigned int*)(ws + 13631488);       // 4,194,304 dw (16.8 MB)
  unsigned short* Eg  = (unsigned short*)(ws + 17825792);    // 8192 u16
  unsigned short* CSg = Eg + 8192;                           // 8192 u16
  unsigned short* Wtb = CSg + 8192;                          // 4096 u16

  hipLaunchKernelGGL(k_prep,   dim3(257),  dim3(256), 0, stream,
                     fw1, fw2, (float2*)wT, Eg, CSg, W, Wtb);
  hipLaunchKernelGGL(k1_mfma,  dim3(4096), dim3(256), 0, stream, x, Eg, Tb);
  hipLaunchKernelGGL(k2_fwd_m, dim3(1024), dim3(256), 0, stream, Tb, Xp);
  hipLaunchKernelGGL(k3_mix,   dim3(512),  dim3(256), 0, stream, Xp, wT, OF);
  hipLaunchKernelGGL(k4_inv_kx,dim3(1024), dim3(256), 0, stream, OF, (uint4*)Gb);
  hipLaunchKernelGGL(k5_mfma,  dim3(4096), dim3(256), 0, stream,
                     (const unsigned short*)Gb, CSg, Wtb, bb, out);
}

// Round 9
// 209.934 us; speedup vs baseline: 1.1511x; 1.1173x over previous
//
#include <hip/hip_runtime.h>
#include <hip/hip_bf16.h>

// FourierLayer2dLite on gfx950.  B=16, M=N=256, I=O=64, NM=16.
// Modes: kx in {0..15,240..255} (a: kx = a<16 ? a : 224+a), ky in [0,16).
// Pipeline (5 launches):
//   k_prep: blocks 0..255 -> wTb[ky][a][i][o] bf16-packed u32; block 256 ->
//           Eg (cos/-sin, pre-scaled 1/256), CSg (cos/+sin), Wtb bf16 tables
//   k1m  : Tb[b][ky][m][i] bf16x2 = E' @ x[b,m,:,:]   (MFMA; swizzled LDS)
//   k23  : fused per (b,ky), 1024 thr:
//          A: partial m-DFT over 4 m-chunks -> LDS   (k2 inner verbatim)
//          B: LDS reduce -> X[a][i]
//          C: OF[b][ky][a][o] = sum_i X*w (w from wTb global, L2-hot)
//   k4   : Gb[b][u][chunk][o] bf16(re,-im)x4ky = c_ky*SC2*sum_a OF e^{+i..}
//   k5m  : Y = CS[256x32] @ Gb';  OUT = relu(Y@W + b + Y)             (MFMA)
// MFMA 16x16x32 bf16: A[m][k]: m=lane&15,k=(lane>>4)*8+j; B[k][n]: n=lane&15;
// C/D: col=lane&15, row=(lane>>4)*4+reg.

#define PI2F 6.283185307179586f

typedef __attribute__((ext_vector_type(8))) short short8v;
typedef __attribute__((ext_vector_type(4))) float f32x4;

static __device__ __forceinline__ unsigned short f_to_bf16(float f) {
  unsigned int u = __float_as_uint(f);
  u += 0x7fffu + ((u >> 16) & 1u);   // RNE (finite values)
  return (unsigned short)(u >> 16);
}
static __device__ __forceinline__ unsigned int pack_bf16(float lo, float hi) {
  return (unsigned int)f_to_bf16(lo) | ((unsigned int)f_to_bf16(hi) << 16);
}

// ---------------- k_prep: wTb (blocks 0..255) + tables (block 256) ----------------
__global__ __launch_bounds__(256) void k_prep(const float* __restrict__ fw1,
                                              const float* __restrict__ fw2,
                                              unsigned int* __restrict__ wTb,
                                              unsigned short* __restrict__ Eg,
                                              unsigned short* __restrict__ CSg,
                                              const float* __restrict__ Wg,
                                              unsigned short* __restrict__ Wtb) {
  int t = threadIdx.x;
  if (blockIdx.x == 256) {             // trig + Wt tables
    const float SC = 1.0f / 256.0f;    // fwd norm folded into E
#pragma unroll
    for (int ky = 0; ky < 16; ++ky) {
      int idx = (ky * t) & 255;
      float ss, cc;
      sincosf(PI2F * (float)idx * (1.0f / 256.0f), &ss, &cc);
      Eg[(2 * ky) * 256 + t]     = f_to_bf16(cc * SC);
      Eg[(2 * ky + 1) * 256 + t] = f_to_bf16(-ss * SC);
      CSg[t * 32 + 2 * ky]       = f_to_bf16(cc);
      CSg[t * 32 + 2 * ky + 1]   = f_to_bf16(ss);
    }
#pragma unroll
    for (int k = 0; k < 16; ++k) {
      int p = k * 256 + t;             // p = i*64 + o
      Wtb[(p & 63) * 64 + (p >> 6)] = f_to_bf16(Wg[p]);
    }
    return;
  }
  int a  = blockIdx.x >> 3;
  int ic = blockIdx.x & 7;
  const float* w = (a < 16) ? fw1 : fw2;
  int xx = a & 15;
#pragma unroll
  for (int k = 0; k < 2; ++k) {
    int p = k * 256 + t;
    int i = ic * 8 + (p >> 6);
    int o = p & 63;
    const float4* s4 = reinterpret_cast<const float4*>(
        w + ((((size_t)i * 64 + o) * 16 + xx) * 16) * 2);
#pragma unroll
    for (int j = 0; j < 8; ++j) {
      float4 q = s4[j];
      wTb[(((size_t)(2 * j) * 32 + a) * 64 + i) * 64 + o]     = pack_bf16(q.x, q.y);
      wTb[(((size_t)(2 * j + 1) * 32 + a) * 64 + i) * 64 + o] = pack_bf16(q.z, q.w);
    }
  }
}

// ---------------- K1 (MFMA): Tb[b,ky,m,i] = E' @ x, bf16 packed ----------------
// grid 4096 = (b,m), 256 thr = 4 waves; wave w owns i-cols 16w..16w+15.
// x staged via double-buffered XOR-swizzled LDS (writes contiguous, reads 2-way).
__global__ __launch_bounds__(256) void k1_mfma(const float* __restrict__ x,
                                               const unsigned short* __restrict__ Eg,
                                               unsigned int* __restrict__ Tb) {
  __shared__ __align__(16) unsigned short El[32 * 264];   // [kc][n], stride 264
  __shared__ __align__(16) float xs[2][2048];             // [n_loc][i] swizzled
  int bm = blockIdx.x;
  int b = bm >> 8, m = bm & 255;
  int tid = threadIdx.x;

  {
    const unsigned int* src = reinterpret_cast<const unsigned int*>(Eg);
    unsigned int* dst = reinterpret_cast<unsigned int*>(El);
#pragma unroll
    for (int t = 0; t < 16; ++t) {
      int idx = t * 256 + tid;              // dw index in [32][128]
      dst[(idx >> 7) * 132 + (idx & 127)] = src[idx];
    }
  }

  const float* xrow = x + (size_t)bm * 16384;
  int lane = tid & 63, w = tid >> 6;
  int r16 = lane & 15, g4 = lane >> 4;

  int r0 = tid >> 4;                   // rows 0..15 (first 4KB)
  int c4 = (tid & 15) * 4;
  int off0 = r0 * 64 + (c4 ^ (((r0 >> 3) & 3) << 4));
  int r1 = 16 + r0;                    // rows 16..31
  int off1 = r1 * 64 + (c4 ^ (((r1 >> 3) & 3) << 4));
  int colr = (w * 16 + r16) ^ (g4 << 4);   // read col (key == g4)

  {  // stage chunk 0
    const float4* s = reinterpret_cast<const float4*>(xrow);
    float4 v0 = s[tid], v1 = s[256 + tid];
    *reinterpret_cast<float4*>(&xs[0][off0]) = v0;
    *reinterpret_cast<float4*>(&xs[0][off1]) = v1;
  }
  __syncthreads();

  f32x4 z = {0.f, 0.f, 0.f, 0.f};
  f32x4 acc0 = z, acc1 = z;

#pragma unroll
  for (int c = 0; c < 8; ++c) {
    int cur = c & 1;
    if (c < 7) {                       // prefetch next chunk into other buffer
      const float4* s = reinterpret_cast<const float4*>(xrow + (c + 1) * 2048);
      float4 v0 = s[tid], v1 = s[256 + tid];
      *reinterpret_cast<float4*>(&xs[cur ^ 1][off0]) = v0;
      *reinterpret_cast<float4*>(&xs[cur ^ 1][off1]) = v1;
    }
    const float* xb = &xs[cur][g4 * 8 * 64 + colr];
    float xv[8];
#pragma unroll
    for (int j = 0; j < 8; ++j) xv[j] = xb[j * 64];
    short8v bfr;
#pragma unroll
    for (int j = 0; j < 8; ++j) bfr[j] = (short)f_to_bf16(xv[j]);
    int nb = c * 32 + g4 * 8;
    short8v a0 = *reinterpret_cast<const short8v*>(&El[r16 * 264 + nb]);
    short8v a1 = *reinterpret_cast<const short8v*>(&El[(16 + r16) * 264 + nb]);
    acc0 = __builtin_amdgcn_mfma_f32_16x16x32_bf16(a0, bfr, acc0, 0, 0, 0);
    acc1 = __builtin_amdgcn_mfma_f32_16x16x32_bf16(a1, bfr, acc1, 0, 0, 0);
    __syncthreads();
  }

  int i = w * 16 + r16;
#pragma unroll
  for (int mt = 0; mt < 2; ++mt) {
    f32x4 av = (mt == 0) ? acc0 : acc1;
    int ky_a = mt * 8 + g4 * 2;
    Tb[((size_t)(b * 16 + ky_a) * 256 + m) * 64 + i]     = pack_bf16(av[0], av[1]);
    Tb[((size_t)(b * 16 + ky_a + 1) * 256 + m) * 64 + i] = pack_bf16(av[2], av[3]);
  }
}

// ---------------- K23 (fused): m-DFT + mode mix, per (b,ky), 1024 thr ----------------
// A: threads (mc4, ih16, ag16) -> partial X over 64 m each (k2 inner verbatim),
//    partials to LDS.  B: reduce 4 partials.  C: threads (a,o) mix over i,
//    X broadcast from LDS, w from wTb global (512B/instr, 16x L2 reuse).
__global__ __launch_bounds__(1024) void k23_mix(const unsigned int* __restrict__ Tb,
                                                const unsigned int* __restrict__ wTb,
                                                float* __restrict__ OF) {
  __shared__ float Xpr[4][2048];       // [mc][a*64+i]
  __shared__ float Xpi[4][2048];
  int bky = blockIdx.x;                // b*16 + ky
  int ky = bky & 15;
  int tid = threadIdx.x;

  // ---- phase A: partial DFT over m-chunk ----
  int mc = tid >> 8, ih = tid & 15, ag = (tid >> 4) & 15;
  int m0 = mc * 64;
  const uint4* Tp4 = reinterpret_cast<const uint4*>(Tb) + (size_t)bky * 4096 + ih;

  float cd1, sd1n, cd2, sd2n;
  { float ss, cc; sincosf(PI2F * (float)ag * (1.0f / 256.0f), &ss, &cc); cd1 = cc; sd1n = -ss; }
  { float ss, cc; sincosf(PI2F * (float)(ag - 16) * (1.0f / 256.0f), &ss, &cc); cd2 = cc; sd2n = -ss; }
  float c1, s1, c2, s2;
  { int t = (ag * m0) & 255; float ss, cc; sincosf(PI2F * (float)t * (1.0f / 256.0f), &ss, &cc); c1 = cc; s1 = -ss; }
  { int t = ((ag + 240) * m0) & 255; float ss, cc; sincosf(PI2F * (float)t * (1.0f / 256.0f), &ss, &cc); c2 = cc; s2 = -ss; }

  float xr1[4], xi1[4], xr2[4], xi2[4];
#pragma unroll
  for (int ii = 0; ii < 4; ++ii) { xr1[ii] = xi1[ii] = xr2[ii] = xi2[ii] = 0.0f; }

#pragma unroll 4
  for (int m = 0; m < 64; ++m) {
    uint4 q = Tp4[(size_t)(m0 + m) * 16];
    unsigned int dv[4] = {q.x, q.y, q.z, q.w};
    float tre[4], tim[4];
#pragma unroll
    for (int ii = 0; ii < 4; ++ii) {
      tre[ii] = __uint_as_float(dv[ii] << 16);
      tim[ii] = __uint_as_float(dv[ii] & 0xffff0000u);
    }
#pragma unroll
    for (int ii = 0; ii < 4; ++ii) {
      xr1[ii] += tre[ii] * c1 - tim[ii] * s1;
      xi1[ii] += tre[ii] * s1 + tim[ii] * c1;
      xr2[ii] += tre[ii] * c2 - tim[ii] * s2;
      xi2[ii] += tre[ii] * s2 + tim[ii] * c2;
    }
    float cn;
    cn = c1 * cd1 - s1 * sd1n; s1 = c1 * sd1n + s1 * cd1; c1 = cn;
    cn = c2 * cd2 - s2 * sd2n; s2 = c2 * sd2n + s2 * cd2; c2 = cn;
  }
#pragma unroll
  for (int ii = 0; ii < 4; ++ii) {
    Xpr[mc][ag * 64 + ih * 4 + ii]        = xr1[ii];
    Xpi[mc][ag * 64 + ih * 4 + ii]        = xi1[ii];
    Xpr[mc][(ag + 16) * 64 + ih * 4 + ii] = xr2[ii];
    Xpi[mc][(ag + 16) * 64 + ih * 4 + ii] = xi2[ii];
  }
  __syncthreads();

  // ---- phase B: reduce 4 partials into plane 0 ----
#pragma unroll
  for (int j = 0; j < 2; ++j) {
    int s = j * 1024 + tid;
    Xpr[0][s] += Xpr[1][s] + Xpr[2][s] + Xpr[3][s];
    Xpi[0][s] += Xpi[1][s] + Xpi[2][s] + Xpi[3][s];
  }
  __syncthreads();

  // ---- phase C: mode mix over i ----
  int o = tid & 63, ab = tid >> 6;     // ab = wave id, uniform per wave
#pragma unroll
  for (int half = 0; half < 2; ++half) {
    int a = ab + half * 16;
    const unsigned int* wp = wTb + (size_t)(ky * 32 + a) * 4096 + o;
    float ore = 0.0f, oim = 0.0f;
    for (int i = 0; i < 64; ++i) {
      float xr = Xpr[0][a * 64 + i];   // broadcast
      float xi = Xpi[0][a * 64 + i];
      unsigned int wv = wp[i * 64];
      float wr = __uint_as_float(wv << 16);
      float wi = __uint_as_float(wv & 0xffff0000u);
      ore += xr * wr - xi * wi;
      oim += xr * wi + xi * wr;
    }
    reinterpret_cast<float2*>(OF)[((size_t)bky * 32 + a) * 64 + o] =
        make_float2(ore, oim);
  }
}

// ---------------- K4: inverse DFT over kx; Gb bf16 [b][u][chunk][o][4ky] ----------------
// grid 1024 = (b, ug of 16 u, ky-chunk of 4). Direct coalesced OF reads (L2-hot);
// only ct/st in LDS. uint4 writes: 1KB contiguous per wave.
__global__ __launch_bounds__(256) void k4_inv_kx(const float* __restrict__ OF,
                                                 uint4* __restrict__ Gb4) {
  int bx = blockIdx.x;
  int b = bx >> 6, ug = (bx >> 2) & 15, chunk = bx & 3;
  __shared__ float ct[256], st[256];
  {
    float ssv, ccv;
    sincosf(PI2F * (float)threadIdx.x * (1.0f / 256.0f), &ssv, &ccv);
    ct[threadIdx.x] = ccv;
    st[threadIdx.x] = ssv;
  }
  __syncthreads();

  int o = threadIdx.x & 63, us = threadIdx.x >> 6;
  int u0 = ug * 16 + us * 4;
  const float SC2 = 0.002772904280510622f;   // sqrt(256*129)/65536
  const float2* OFb = reinterpret_cast<const float2*>(OF) +
                      ((size_t)b * 16 + chunk * 4) * 2048;   // [4ky][32a][64o]

  float accr[4][4], acci[4][4];
#pragma unroll
  for (int du = 0; du < 4; ++du)
#pragma unroll
    for (int kyl = 0; kyl < 4; ++kyl) { accr[du][kyl] = 0.0f; acci[du][kyl] = 0.0f; }

  for (int a = 0; a < 32; ++a) {
    int kx = (a < 16) ? a : (224 + a);
    float ofr[4], ofi[4];
#pragma unroll
    for (int kyl = 0; kyl < 4; ++kyl) {
      float2 v = OFb[(kyl * 32 + a) * 64 + o];
      ofr[kyl] = v.x; ofi[kyl] = v.y;
    }
#pragma unroll
    for (int du = 0; du < 4; ++du) {
      int t = (kx * (u0 + du)) & 255;
      float cv = ct[t], sv = st[t];
#pragma unroll
      for (int kyl = 0; kyl < 4; ++kyl) {
        accr[du][kyl] += ofr[kyl] * cv - ofi[kyl] * sv;
        acci[du][kyl] += ofr[kyl] * sv + ofi[kyl] * cv;
      }
    }
  }
#pragma unroll
  for (int du = 0; du < 4; ++du) {
    int u = u0 + du;
    unsigned int wv[4];
#pragma unroll
    for (int kyl = 0; kyl < 4; ++kyl) {
      int ky = chunk * 4 + kyl;
      float sc = SC2 * ((ky == 0) ? 1.0f : 2.0f);
      wv[kyl] = pack_bf16(accr[du][kyl] * sc, -acci[du][kyl] * sc);
    }
    uint4 pk; pk.x = wv[0]; pk.y = wv[1]; pk.z = wv[2]; pk.w = wv[3];
    Gb4[(((size_t)b * 256 + u) * 4 + chunk) * 64 + o] = pk;
  }
}

// ---------------- K5 (MFMA): Y = CS @ G'; OUT = relu(Y@W + b + Y) ----------------
// grid 4096 = (b,u), 256 thr = 4 waves; wave w owns v-rows 64w..64w+63.
// Gb layout [b][u][chunk][o][4ky]: lane (g4,r16) reads chunk=g4 -> coalesced.
__global__ __launch_bounds__(256) void k5_mfma(const unsigned short* __restrict__ Gb,
                                               const unsigned short* __restrict__ CSg,
                                               const unsigned short* __restrict__ Wtb,
                                               const float* __restrict__ bias,
                                               float* __restrict__ out) {
  __shared__ __align__(16) unsigned short yl[256 * 72];   // 36864 B

  int blk = blockIdx.x;
  int tid = threadIdx.x;
  int lane = tid & 63, w = tid >> 6;
  int r16 = lane & 15, g4 = lane >> 4;
  int kc0 = g4 * 8;

  f32x4 z = {0.f, 0.f, 0.f, 0.f};
  f32x4 acc[4][4];

  // ---- phase A: A = CS rows v, B = G' rows kc cols o ----
  short8v af[4], bfx[4];
#pragma unroll
  for (int vt = 0; vt < 4; ++vt)
    af[vt] = *reinterpret_cast<const short8v*>(&CSg[(w * 64 + vt * 16 + r16) * 32 + kc0]);
#pragma unroll
  for (int ot = 0; ot < 4; ++ot)
    bfx[ot] = *reinterpret_cast<const short8v*>(
        &Gb[(((size_t)blk * 4 + g4) * 64 + ot * 16 + r16) * 8]);
#pragma unroll
  for (int vt = 0; vt < 4; ++vt)
#pragma unroll
    for (int ot = 0; ot < 4; ++ot)
      acc[vt][ot] = __builtin_amdgcn_mfma_f32_16x16x32_bf16(af[vt], bfx[ot], z, 0, 0, 0);

  // Y -> LDS bf16 (own-wave rows only)
#pragma unroll
  for (int vt = 0; vt < 4; ++vt)
#pragma unroll
    for (int ot = 0; ot < 4; ++ot)
#pragma unroll
      for (int r = 0; r < 4; ++r)
        yl[(w * 64 + vt * 16 + g4 * 4 + r) * 72 + ot * 16 + r16] = f_to_bf16(acc[vt][ot][r]);

  // ---- phase B: acc += bias, then += Y @ W ----
#pragma unroll
  for (int ot = 0; ot < 4; ++ot) {
    float bv = bias[ot * 16 + r16];
#pragma unroll
    for (int vt = 0; vt < 4; ++vt)
#pragma unroll
      for (int r = 0; r < 4; ++r) acc[vt][ot][r] += bv;
  }

#pragma unroll
  for (int ks = 0; ks < 2; ++ks) {
    int k0 = ks * 32 + kc0;
    short8v ya[4], wb[4];
#pragma unroll
    for (int vt = 0; vt < 4; ++vt)
      ya[vt] = *reinterpret_cast<const short8v*>(&yl[(w * 64 + vt * 16 + r16) * 72 + k0]);
#pragma unroll
    for (int ot = 0; ot < 4; ++ot)
      wb[ot] = *reinterpret_cast<const short8v*>(&Wtb[(ot * 16 + r16) * 64 + k0]);
#pragma unroll
    for (int vt = 0; vt < 4; ++vt)
#pragma unroll
      for (int ot = 0; ot < 4; ++ot)
        acc[vt][ot] = __builtin_amdgcn_mfma_f32_16x16x32_bf16(ya[vt], wb[ot], acc[vt][ot], 0, 0, 0);
  }

  // ---- epilogue: relu -> wave-local LDS transpose -> coalesced float4 stores ----
  float* ob = out + (size_t)blk * 16384;
  float* tw = reinterpret_cast<float*>(&yl[w * 4608]);   // own 9216B region, reuse
#pragma unroll
  for (int vt = 0; vt < 4; ++vt) {
#pragma unroll
    for (int ot = 0; ot < 4; ++ot)
#pragma unroll
      for (int r = 0; r < 4; ++r)
        tw[(g4 * 4 + r) * 68 + ot * 16 + r16] = fmaxf(acc[vt][ot][r], 0.0f);
    float* obase = ob + (size_t)(w * 64 + vt * 16) * 64;
#pragma unroll
    for (int q = 0; q < 4; ++q) {
      float4 vv = *reinterpret_cast<const float4*>(
          &tw[(q * 4 + (lane >> 4)) * 68 + (lane & 15) * 4]);
      *reinterpret_cast<float4*>(&obase[q * 256 + lane * 4]) = vv;
    }
  }
}

extern "C" void kernel_launch(void* const* d_in, const int* in_sizes, int n_in,
                              void* d_out, int out_size, void* d_ws, size_t ws_size,
                              hipStream_t stream) {
  const float* x   = (const float*)d_in[0];
  const float* fw1 = (const float*)d_in[1];
  const float* fw2 = (const float*)d_in[2];
  const float* W   = (const float*)d_in[3];
  const float* bb  = (const float*)d_in[4];
  float* out = (float*)d_out;

  float* ws = (float*)d_ws;
  unsigned int* wTb  = (unsigned int*)ws;                    // 2,097,152 u32 (8.4 MB)
  unsigned int* Tb   = (unsigned int*)(ws + 2097152);        // 4,194,304 dw (16.8 MB)
  float* OF          = ws + 6291456;                         // 1,048,576 f  (4.2 MB)
  unsigned int* Gb   = (unsigned int*)(ws + 7340032);        // 4,194,304 dw (16.8 MB)
  unsigned short* Eg  = (unsigned short*)(ws + 11534336);    // 8192 u16
  unsigned short* CSg = Eg + 8192;                           // 8192 u16
  unsigned short* Wtb = CSg + 8192;                          // 4096 u16

  hipLaunchKernelGGL(k_prep,   dim3(257),  dim3(256),  0, stream,
                     fw1, fw2, wTb, Eg, CSg, W, Wtb);
  hipLaunchKernelGGL(k1_mfma,  dim3(4096), dim3(256),  0, stream, x, Eg, Tb);
  hipLaunchKernelGGL(k23_mix,  dim3(256),  dim3(1024), 0, stream, Tb, wTb, OF);
  hipLaunchKernelGGL(k4_inv_kx,dim3(1024), dim3(256),  0, stream, OF, (uint4*)Gb);
  hipLaunchKernelGGL(k5_mfma,  dim3(4096), dim3(256),  0, stream,
                     (const unsigned short*)Gb, CSg, Wtb, bb, out);
}